// Round 1
// baseline (673.225 us; speedup 1.0000x reference)
//
#include <hip/hip_runtime.h>
#include <cstdint>

// ChessRelativeTransformer on MI355X (gfx950), bf16 MFMA pipeline.
// B=512 T=64 H=16 DH=64 D=1024 NUM_REL=225 scale=0.125
//
// ws layout (bytes, needs ~459 MB):
//   0      : xb  (x in bf16, 64MB)  -- later reused as P buffer
//   64MB   : Qb  [b][h][t][d] bf16
//   128MB  : Kb  [b][h][t][d] bf16
//   192MB  : Vtb [b][h][d][t] bf16 (transposed for PV)
//   256MB  : bias1 [b][h][t][s] bf16  (q·rel_k + relq_relk)
//   320MB  : bias2 [b][h][s][t] bf16  (rel_q·k)
//   384MB  : attn_out [b*64+t][h*64+d] bf16
//   448MB  : Wqkv bf16 [3072][1024]
//   454MB  : Wo bf16 [1024][1024]
//   456/457/458MB : rel_q / rel_k / rel_v bf16 [16][225][64]

typedef unsigned short u16;
typedef unsigned int u32;
typedef __bf16 bf16x8 __attribute__((ext_vector_type(8)));
typedef float f32x4 __attribute__((ext_vector_type(4)));

#define MFMA16(a, b, c) __builtin_amdgcn_mfma_f32_16x16x32_bf16(a, b, c, 0, 0, 0)

__device__ __forceinline__ u16 f2bf(float f) {
  u32 u = __builtin_bit_cast(u32, f);
  u = (u + 0x7FFFu + ((u >> 16) & 1u)) >> 16;
  return (u16)u;
}
__device__ __forceinline__ float bf2f(u16 h) {
  return __builtin_bit_cast(float, ((u32)h) << 16);
}

// async global->LDS, 16B per lane; lds_wave_base must be wave-uniform,
// HW places lane i at base + i*16.
__device__ __forceinline__ void g2l16(const void* g, void* lds_wave_base) {
#if __has_builtin(__builtin_amdgcn_global_load_lds)
  __builtin_amdgcn_global_load_lds(
      (const __attribute__((address_space(1))) u32*)(uintptr_t)g,
      (__attribute__((address_space(3))) u32*)(uintptr_t)lds_wave_base, 16, 0, 0);
#else
  uint4 v = *(const uint4*)g;
  *(uint4*)((char*)lds_wave_base + (threadIdx.x & 63) * 16) = v;
#endif
}

// ---------------- fp32 -> bf16 convert (4 elems/thread) ----------------
__global__ __launch_bounds__(256) void k_cvt(const float* __restrict__ src,
                                             u16* __restrict__ dst, int nq) {
  int i = blockIdx.x * 256 + threadIdx.x;
  if (i >= nq) return;
  float4 v = ((const float4*)src)[i];
  ushort4 o;
  o.x = f2bf(v.x); o.y = f2bf(v.y); o.z = f2bf(v.z); o.w = f2bf(v.w);
  ((ushort4*)dst)[i] = o;
}

// ---------------- QKV GEMM: [32768x1024] x [3072x1024]^T ----------------
// 128x128 tile, BK=32, 4 waves, global_load_lds + XOR swizzle ((r>>1)&3 on 16B slots).
__global__ __launch_bounds__(256) void k_gemm_qkv(
    const u16* __restrict__ A, const u16* __restrict__ Bm,
    const float* __restrict__ bq, const float* __restrict__ bk,
    const float* __restrict__ bv, u16* __restrict__ Qb, u16* __restrict__ Kb,
    u16* __restrict__ Vtb) {
  __shared__ char lds[16384];
  const int tid = threadIdx.x;
  const int lane = tid & 63, w = tid >> 6;
  const int wr = w >> 1, wc = w & 1;
  const int l15 = lane & 15, l4 = lane >> 4;
  const int row0 = blockIdx.y * 128, col0 = blockIdx.x * 128;
  f32x4 acc[4][4] = {};

  for (int kk = 0; kk < 1024; kk += 32) {
    __syncthreads();
#pragma unroll
    for (int c = 0; c < 2; c++) {
      int ch = c * 256 + tid;
      int r = ch >> 2;
      int sl = (ch & 3) ^ ((r >> 1) & 3);
      g2l16(A + (size_t)(row0 + r) * 1024 + kk + sl * 8,
            lds + c * 4096 + w * 1024);
      g2l16(Bm + (size_t)(col0 + r) * 1024 + kk + sl * 8,
            lds + 8192 + c * 4096 + w * 1024);
    }
    __syncthreads();
    bf16x8 af[4], bff[4];
#pragma unroll
    for (int m = 0; m < 4; m++) {
      int r = wr * 64 + m * 16 + l15;
      int sl = l4 ^ ((r >> 1) & 3);
      af[m] = *(const bf16x8*)(lds + r * 64 + sl * 16);
    }
#pragma unroll
    for (int n = 0; n < 4; n++) {
      int r = wc * 64 + n * 16 + l15;
      int sl = l4 ^ ((r >> 1) & 3);
      bff[n] = *(const bf16x8*)(lds + 8192 + r * 64 + sl * 16);
    }
#pragma unroll
    for (int m = 0; m < 4; m++)
#pragma unroll
      for (int n = 0; n < 4; n++)
        acc[m][n] = MFMA16(af[m], bff[n], acc[m][n]);
  }
  // epilogue: scatter to Q/K (b,h,t,d) and V transposed (b,h,d,t), + bias
#pragma unroll
  for (int n = 0; n < 4; n++) {
    int col = col0 + wc * 64 + n * 16 + l15;
    int sel = col >> 10, hd = col & 1023;
    int h = hd >> 6, d = hd & 63;
    const float* bp = (sel == 0) ? bq : (sel == 1) ? bk : bv;
    float bias = bp[hd];
    u16* dst = (sel == 0) ? Qb : (sel == 1) ? Kb : Vtb;
#pragma unroll
    for (int m = 0; m < 4; m++) {
      int rowb = row0 + wr * 64 + m * 16 + l4 * 4;
#pragma unroll
      for (int j = 0; j < 4; j++) {
        int row = rowb + j;
        int b = row >> 6, t = row & 63;
        size_t off = (sel == 2)
                         ? ((size_t)(b * 16 + h)) * 4096 + d * 64 + t
                         : ((size_t)(b * 16 + h)) * 4096 + t * 64 + d;
        dst[off] = f2bf(acc[m][n][j] + bias);
      }
    }
  }
}

// ---------------- output GEMM: [32768x1024] x [1024x1024]^T + bias -> fp32 ----
__global__ __launch_bounds__(256) void k_gemm_out(
    const u16* __restrict__ A, const u16* __restrict__ Bm,
    const float* __restrict__ bo, float* __restrict__ out) {
  __shared__ char lds[16384];
  const int tid = threadIdx.x;
  const int lane = tid & 63, w = tid >> 6;
  const int wr = w >> 1, wc = w & 1;
  const int l15 = lane & 15, l4 = lane >> 4;
  const int row0 = blockIdx.y * 128, col0 = blockIdx.x * 128;
  f32x4 acc[4][4] = {};

  for (int kk = 0; kk < 1024; kk += 32) {
    __syncthreads();
#pragma unroll
    for (int c = 0; c < 2; c++) {
      int ch = c * 256 + tid;
      int r = ch >> 2;
      int sl = (ch & 3) ^ ((r >> 1) & 3);
      g2l16(A + (size_t)(row0 + r) * 1024 + kk + sl * 8,
            lds + c * 4096 + w * 1024);
      g2l16(Bm + (size_t)(col0 + r) * 1024 + kk + sl * 8,
            lds + 8192 + c * 4096 + w * 1024);
    }
    __syncthreads();
    bf16x8 af[4], bff[4];
#pragma unroll
    for (int m = 0; m < 4; m++) {
      int r = wr * 64 + m * 16 + l15;
      int sl = l4 ^ ((r >> 1) & 3);
      af[m] = *(const bf16x8*)(lds + r * 64 + sl * 16);
    }
#pragma unroll
    for (int n = 0; n < 4; n++) {
      int r = wc * 64 + n * 16 + l15;
      int sl = l4 ^ ((r >> 1) & 3);
      bff[n] = *(const bf16x8*)(lds + 8192 + r * 64 + sl * 16);
    }
#pragma unroll
    for (int m = 0; m < 4; m++)
#pragma unroll
      for (int n = 0; n < 4; n++)
        acc[m][n] = MFMA16(af[m], bff[n], acc[m][n]);
  }
#pragma unroll
  for (int n = 0; n < 4; n++) {
    int col = col0 + wc * 64 + n * 16 + l15;
    float bias = bo[col];
#pragma unroll
    for (int m = 0; m < 4; m++) {
      int rowb = row0 + wr * 64 + m * 16 + l4 * 4;
#pragma unroll
      for (int j = 0; j < 4; j++)
        out[(size_t)(rowb + j) * 1024 + col] = acc[m][n][j] + bias;
    }
  }
}

// ---------------- bias1[b,h,t,s] = sum_d q[b,h,t,d]*rel_k[h,idx[t,s],d] + T3[h,t,s]
// grid (t=64, h=16, bc=2); per block: (256 b-rows) x 64 s, K=64
__global__ __launch_bounds__(256) void k_bias1(
    const u16* __restrict__ Qb, const u16* __restrict__ relq,
    const u16* __restrict__ relk, const int* __restrict__ relidx,
    u16* __restrict__ bias1) {
  const int tid = threadIdx.x, lane = tid & 63, w = tid >> 6;
  const int l15 = lane & 15, l4 = lane >> 4;
  const int t = blockIdx.x, h = blockIdx.y, bc = blockIdx.z;
  __shared__ char lds[16640];
  char* RK = lds;
  char* RQ = lds + 8192;
  float* T3 = (float*)(lds + 16384);
#pragma unroll
  for (int c = 0; c < 2; c++) {
    int ch = c * 256 + tid;
    int sr = ch >> 3, sl = (ch & 7) ^ (sr & 7);
    int ri = relidx[t * 64 + sr];
    size_t so = ((size_t)h * 225 + ri) * 64 + sl * 8;
    g2l16(relk + so, RK + c * 4096 + w * 1024);
    g2l16(relq + so, RQ + c * 4096 + w * 1024);
  }
  __syncthreads();
  if (tid < 64) {
    int sr = tid;
    float sum = 0.f;
#pragma unroll
    for (int sl = 0; sl < 8; sl++) {
      int o = sr * 128 + ((sl ^ (sr & 7)) << 4);
      bf16x8 aq = *(const bf16x8*)(RQ + o);
      bf16x8 ak = *(const bf16x8*)(RK + o);
#pragma unroll
      for (int j = 0; j < 8; j++) sum += (float)aq[j] * (float)ak[j];
    }
    T3[sr] = sum;
  }
  bf16x8 bfr[4][2];
#pragma unroll
  for (int n = 0; n < 4; n++)
#pragma unroll
    for (int kh = 0; kh < 2; kh++) {
      int r = n * 16 + l15;
      int sl = ((kh << 2) + l4) ^ (r & 7);
      bfr[n][kh] = *(const bf16x8*)(RK + r * 128 + sl * 16);
    }
  __syncthreads();
  f32x4 acc[4][4] = {};
#pragma unroll
  for (int m = 0; m < 4; m++) {
    int bb = bc * 256 + w * 64 + m * 16 + l15;
    const u16* ap = Qb + ((size_t)(bb * 16 + h)) * 4096 + t * 64 + l4 * 8;
    bf16x8 a0 = *(const bf16x8*)ap;
    bf16x8 a1 = *(const bf16x8*)(ap + 32);
#pragma unroll
    for (int n = 0; n < 4; n++) {
      acc[m][n] = MFMA16(a0, bfr[n][0], acc[m][n]);
      acc[m][n] = MFMA16(a1, bfr[n][1], acc[m][n]);
    }
  }
#pragma unroll
  for (int m = 0; m < 4; m++)
#pragma unroll
    for (int n = 0; n < 4; n++)
#pragma unroll
      for (int j = 0; j < 4; j++) {
        int bb = bc * 256 + w * 64 + m * 16 + l4 * 4 + j;
        int s_ = n * 16 + l15;
        bias1[((size_t)(bb * 16 + h)) * 4096 + t * 64 + s_] =
            f2bf(acc[m][n][j] + T3[s_]);
      }
}

// ---------------- bias2[b,h,s,t] = sum_d rel_q[h,idx[t,s],d]*k[b,h,s,d]
// grid (s=64, h=16, bc=2)
__global__ __launch_bounds__(256) void k_bias2(
    const u16* __restrict__ Kb, const u16* __restrict__ relq,
    const int* __restrict__ relidx, u16* __restrict__ bias2) {
  const int tid = threadIdx.x, lane = tid & 63, w = tid >> 6;
  const int l15 = lane & 15, l4 = lane >> 4;
  const int s = blockIdx.x, h = blockIdx.y, bc = blockIdx.z;
  __shared__ char lds[8192];
#pragma unroll
  for (int c = 0; c < 2; c++) {
    int ch = c * 256 + tid;
    int tq = ch >> 3, sl = (ch & 7) ^ (tq & 7);
    int ri = relidx[tq * 64 + s];
    g2l16(relq + ((size_t)h * 225 + ri) * 64 + sl * 8,
          lds + c * 4096 + w * 1024);
  }
  __syncthreads();
  bf16x8 bfr[4][2];
#pragma unroll
  for (int n = 0; n < 4; n++)
#pragma unroll
    for (int kh = 0; kh < 2; kh++) {
      int r = n * 16 + l15;
      int sl = ((kh << 2) + l4) ^ (r & 7);
      bfr[n][kh] = *(const bf16x8*)(lds + r * 128 + sl * 16);
    }
  f32x4 acc[4][4] = {};
#pragma unroll
  for (int m = 0; m < 4; m++) {
    int bb = bc * 256 + w * 64 + m * 16 + l15;
    const u16* ap = Kb + ((size_t)(bb * 16 + h)) * 4096 + s * 64 + l4 * 8;
    bf16x8 a0 = *(const bf16x8*)ap;
    bf16x8 a1 = *(const bf16x8*)(ap + 32);
#pragma unroll
    for (int n = 0; n < 4; n++) {
      acc[m][n] = MFMA16(a0, bfr[n][0], acc[m][n]);
      acc[m][n] = MFMA16(a1, bfr[n][1], acc[m][n]);
    }
  }
#pragma unroll
  for (int m = 0; m < 4; m++)
#pragma unroll
    for (int n = 0; n < 4; n++)
#pragma unroll
      for (int j = 0; j < 4; j++) {
        int bb = bc * 256 + w * 64 + m * 16 + l4 * 4 + j;
        int tcol = n * 16 + l15;
        bias2[((size_t)(bb * 16 + h)) * 4096 + s * 64 + tcol] =
            f2bf(acc[m][n][j]);
      }
}

// ---------------- attention per (b,h): S=QK^T + b1 + b2^T, softmax, P, PV ----
__global__ __launch_bounds__(256) void k_attn(
    const u16* __restrict__ Qb, const u16* __restrict__ Kb,
    const u16* __restrict__ Vtb, const u16* __restrict__ b1g,
    const u16* __restrict__ b2g, u16* __restrict__ Pg,
    u16* __restrict__ aout) {
  const int tid = threadIdx.x, lane = tid & 63, w = tid >> 6;
  const int l15 = lane & 15, l4 = lane >> 4;
  const int b = blockIdx.x, h = blockIdx.y;
  __shared__ char lds[49152];
  char* Qt = lds;
  char* Kt = lds + 8192;
  char* Vt = lds + 16384;
  char* B1 = lds + 24576;
  char* B2 = lds + 32768;
  char* Pt = lds + 40960;
  const size_t base = ((size_t)(b * 16 + h)) * 4096;
#pragma unroll
  for (int c = 0; c < 2; c++) {
    int ch = c * 256 + tid;
    int r = ch >> 3, sl = (ch & 7) ^ (r & 7);
    size_t so = base + r * 64 + sl * 8;
    int dst = c * 4096 + w * 1024;
    g2l16(Qb + so, Qt + dst);
    g2l16(Kb + so, Kt + dst);
    g2l16(Vtb + so, Vt + dst);
    g2l16(b1g + so, B1 + dst);
    g2l16(b2g + so, B2 + dst);
  }
  __syncthreads();
  // S = Q K^T, wave w owns rows [w*16, w*16+16)
  f32x4 acc[4] = {};
  bf16x8 qf[2];
  {
    int r = w * 16 + l15;
#pragma unroll
    for (int kh = 0; kh < 2; kh++) {
      int sl = ((kh << 2) + l4) ^ (r & 7);
      qf[kh] = *(const bf16x8*)(Qt + r * 128 + sl * 16);
    }
  }
#pragma unroll
  for (int n = 0; n < 4; n++) {
    int r = n * 16 + l15;
#pragma unroll
    for (int kh = 0; kh < 2; kh++) {
      int sl = ((kh << 2) + l4) ^ (r & 7);
      bf16x8 kf = *(const bf16x8*)(Kt + r * 128 + sl * 16);
      acc[n] = MFMA16(qf[kh], kf, acc[n]);
    }
  }
  const int t0 = w * 16 + l4 * 4;
#pragma unroll
  for (int j = 0; j < 4; j++) {
    int t_ = t0 + j;
    float lv[4];
#pragma unroll
    for (int n = 0; n < 4; n++) {
      int s_ = n * 16 + l15;
      float x = acc[n][j];
      x += bf2f(*(const u16*)(B1 + t_ * 128 + ((s_ * 2) ^ ((t_ & 7) << 4))));
      x += bf2f(*(const u16*)(B2 + s_ * 128 + ((t_ * 2) ^ ((s_ & 7) << 4))));
      lv[n] = x * 0.125f;
    }
    float mx = fmaxf(fmaxf(lv[0], lv[1]), fmaxf(lv[2], lv[3]));
#pragma unroll
    for (int d = 1; d < 16; d <<= 1) mx = fmaxf(mx, __shfl_xor(mx, d, 64));
    float e0 = __expf(lv[0] - mx), e1 = __expf(lv[1] - mx);
    float e2 = __expf(lv[2] - mx), e3 = __expf(lv[3] - mx);
    float sum = e0 + e1 + e2 + e3;
#pragma unroll
    for (int d = 1; d < 16; d <<= 1) sum += __shfl_xor(sum, d, 64);
    float inv = 1.0f / sum;
    float pe[4] = {e0 * inv, e1 * inv, e2 * inv, e3 * inv};
#pragma unroll
    for (int n = 0; n < 4; n++) {
      int s_ = n * 16 + l15;
      *(u16*)(Pt + t_ * 128 + ((s_ * 2) ^ ((t_ & 7) << 4))) = f2bf(pe[n]);
    }
  }
  __syncthreads();
  // P -> global (linearized, undo swizzle)
#pragma unroll
  for (int c = 0; c < 2; c++) {
    int ch = c * 256 + tid;
    int r = ch >> 3, sl = ch & 7;
    uint4 v = *(const uint4*)(Pt + r * 128 + ((sl ^ (r & 7)) << 4));
    *((uint4*)(Pg + base) + ch) = v;
  }
  // out_v = P * V  (V staged transposed: Vt[d][t])
  f32x4 acc2[4] = {};
  bf16x8 pf[2];
  {
    int r = w * 16 + l15;
#pragma unroll
    for (int kh = 0; kh < 2; kh++) {
      int sl = ((kh << 2) + l4) ^ (r & 7);
      pf[kh] = *(const bf16x8*)(Pt + r * 128 + sl * 16);
    }
  }
#pragma unroll
  for (int n = 0; n < 4; n++) {
    int r = n * 16 + l15;  // d row
#pragma unroll
    for (int kh = 0; kh < 2; kh++) {
      int sl = ((kh << 2) + l4) ^ (r & 7);
      bf16x8 vf = *(const bf16x8*)(Vt + r * 128 + sl * 16);
      acc2[n] = MFMA16(pf[kh], vf, acc2[n]);
    }
  }
#pragma unroll
  for (int n = 0; n < 4; n++)
#pragma unroll
    for (int j = 0; j < 4; j++) {
      int t_ = t0 + j, d_ = n * 16 + l15;
      aout[((size_t)(b * 64 + t_)) * 1024 + h * 64 + d_] = f2bf(acc2[n][j]);
    }
}

// ---------------- out_relv: per (h,t): aout[b,t,h,d] += sum_s P[b,s]*rel_v[h,idx[t,s],d]
__global__ __launch_bounds__(256) void k_relv(
    const u16* __restrict__ Pg, const u16* __restrict__ relv,
    const int* __restrict__ relidx, u16* __restrict__ aout) {
  const int tid = threadIdx.x, lane = tid & 63, w = tid >> 6;
  const int l15 = lane & 15, l4 = lane >> 4;
  const int t = blockIdx.x, h = blockIdx.y, bc = blockIdx.z;
  __shared__ char lds[8192];
#pragma unroll
  for (int c = 0; c < 2; c++) {
    int ch = c * 256 + tid;
    int sr = ch >> 3, sl = (ch & 7) ^ (sr & 7);
    int ri = relidx[t * 64 + sr];
    g2l16(relv + ((size_t)h * 225 + ri) * 64 + sl * 8,
          lds + c * 4096 + w * 1024);
  }
  __syncthreads();
  // B operand needs column slices rv[s][d] with s varying per lane-elem -> scalar reads
  bf16x8 bfr[4][2];
#pragma unroll
  for (int n = 0; n < 4; n++)
#pragma unroll
    for (int kh = 0; kh < 2; kh++) {
      bf16x8 tmp;
#pragma unroll
      for (int j = 0; j < 8; j++) {
        int s_ = (kh << 5) + (l4 << 3) + j;
        int d_ = n * 16 + l15;
        u16 u = *(const u16*)(lds + s_ * 128 + ((d_ * 2) ^ ((s_ & 7) << 4)));
        tmp[j] = __builtin_bit_cast(__bf16, u);
      }
      bfr[n][kh] = tmp;
    }
  f32x4 acc[4][4] = {};
#pragma unroll
  for (int m = 0; m < 4; m++) {
    int bb = bc * 256 + w * 64 + m * 16 + l15;
    const u16* ap = Pg + ((size_t)(bb * 16 + h)) * 4096 + t * 64 + l4 * 8;
    bf16x8 a0 = *(const bf16x8*)ap;
    bf16x8 a1 = *(const bf16x8*)(ap + 32);
#pragma unroll
    for (int n = 0; n < 4; n++) {
      acc[m][n] = MFMA16(a0, bfr[n][0], acc[m][n]);
      acc[m][n] = MFMA16(a1, bfr[n][1], acc[m][n]);
    }
  }
#pragma unroll
  for (int m = 0; m < 4; m++)
#pragma unroll
    for (int n = 0; n < 4; n++)
#pragma unroll
      for (int j = 0; j < 4; j++) {
        int bb = bc * 256 + w * 64 + m * 16 + l4 * 4 + j;
        int d_ = n * 16 + l15;
        size_t o = ((size_t)(bb * 64 + t)) * 1024 + h * 64 + d_;
        aout[o] = f2bf(bf2f(aout[o]) + acc[m][n][j]);
      }
}

extern "C" void kernel_launch(void* const* d_in, const int* in_sizes, int n_in,
                              void* d_out, int out_size, void* d_ws,
                              size_t ws_size, hipStream_t stream) {
  const float* x = (const float*)d_in[0];
  const float* Wq = (const float*)d_in[1];
  const float* bq = (const float*)d_in[2];
  const float* Wk = (const float*)d_in[3];
  const float* bk = (const float*)d_in[4];
  const float* Wv = (const float*)d_in[5];
  const float* bv = (const float*)d_in[6];
  const float* Wo = (const float*)d_in[7];
  const float* bo = (const float*)d_in[8];
  const float* rq = (const float*)d_in[9];
  const float* rk = (const float*)d_in[10];
  const float* rv = (const float*)d_in[11];
  const int* ridx = (const int*)d_in[12];
  float* out = (float*)d_out;

  char* ws = (char*)d_ws;
  const size_t MB = 1ull << 20;
  u16* xb = (u16*)(ws + 0);  // reused as P after k_gemm_qkv consumes it
  u16* Qb = (u16*)(ws + 64 * MB);
  u16* Kb = (u16*)(ws + 128 * MB);
  u16* Vtb = (u16*)(ws + 192 * MB);
  u16* b1 = (u16*)(ws + 256 * MB);
  u16* b2 = (u16*)(ws + 320 * MB);
  u16* aout = (u16*)(ws + 384 * MB);
  u16* wqkv = (u16*)(ws + 448 * MB);
  u16* wo = (u16*)(ws + 454 * MB);
  u16* relq = (u16*)(ws + 456 * MB);
  u16* relk = (u16*)(ws + 457 * MB);
  u16* relv = (u16*)(ws + 458 * MB);
  u16* Pg = xb;

  k_cvt<<<32768, 256, 0, stream>>>(x, xb, 8388608);
  k_cvt<<<1024, 256, 0, stream>>>(Wq, wqkv, 262144);
  k_cvt<<<1024, 256, 0, stream>>>(Wk, wqkv + 1048576, 262144);
  k_cvt<<<1024, 256, 0, stream>>>(Wv, wqkv + 2097152, 262144);
  k_cvt<<<1024, 256, 0, stream>>>(Wo, wo, 262144);
  k_cvt<<<225, 256, 0, stream>>>(rq, relq, 57600);
  k_cvt<<<225, 256, 0, stream>>>(rk, relk, 57600);
  k_cvt<<<225, 256, 0, stream>>>(rv, relv, 57600);

  k_gemm_qkv<<<dim3(24, 256), 256, 0, stream>>>(xb, wqkv, bq, bk, bv, Qb, Kb,
                                                Vtb);
  k_bias1<<<dim3(64, 16, 2), 256, 0, stream>>>(Qb, relq, relk, ridx, b1);
  k_bias2<<<dim3(64, 16, 2), 256, 0, stream>>>(Kb, relq, ridx, b2);
  k_attn<<<dim3(512, 16), 256, 0, stream>>>(Qb, Kb, Vtb, b1, b2, Pg, aout);
  k_relv<<<dim3(64, 16, 2), 256, 0, stream>>>(Pg, relv, ridx, aout);
  k_gemm_out<<<dim3(8, 256), 256, 0, stream>>>(aout, wo, bo, out);
}